// Round 10
// baseline (488.792 us; speedup 1.0000x reference)
//
#include <hip/hip_runtime.h>
#include <stdint.h>

#define GRID_SZ 0.05f
#define BN_EPS 1e-5f

typedef __attribute__((ext_vector_type(8))) short bf16x8;
typedef __attribute__((ext_vector_type(4))) float f32x4;

// ---------------- ws layout (byte offsets) ----------------
#define WS_START   0         // 12 uints
#define WS_DIMS    64        // 3 ints
#define WS_CHSUM   128       // 256 f
#define WS_CHSQ    1152
#define WS_AC      2176
#define WS_BC      3200
#define WS_W1B     4224      // 256*128 bf16 = 65536
#define WS_W2B     69760     // 256*256 bf16 = 131072
#define WS_GRAM    200832    // 128*128 f = 65536
#define WS_CSUM    266368    // 128 f = 512
#define WS_HIST    266880    // 65536 ints = 262144
#define WS_RANK    529024    // 65537 ints (+pad) = 262208
#define WS_CURS    791296    // 65536 ints = 262144
#define WS_BSUM    1053440   // 64 int2 = 512
#define WS_XYZS    1053952   // 65536*3 f = 786432
#define WS_LIN     1840384   // N ints
#define WS_PERM    2640384   // N ints
#define WS_XB      3440384   // N*128 bf16

__device__ __forceinline__ short f2bf(float f) {
  unsigned u = __float_as_uint(f);
  u += 0x7FFFu + ((u >> 16) & 1u);   // round-to-nearest-even
  return (short)(u >> 16);
}

__device__ __forceinline__ bf16x8 load_frag(const float* p) {
  f32x4 a = *(const f32x4*)p;
  f32x4 b = *(const f32x4*)(p + 4);
  bf16x8 r;
  r[0] = f2bf(a[0]); r[1] = f2bf(a[1]); r[2] = f2bf(a[2]); r[3] = f2bf(a[3]);
  r[4] = f2bf(b[0]); r[5] = f2bf(b[1]); r[6] = f2bf(b[2]); r[7] = f2bf(b[3]);
  return r;
}

__device__ __forceinline__ int batch_of(int p, const int* offs, int nb) {
  int b = 0;
  while (b < nb - 1 && p >= offs[b]) b++;
  return b;
}

// ---------------- init + weight conversion (fused) ----------------
__global__ void k_init(unsigned* featU, size_t featN, int* hist, float* xyzs,
                       float* chsum, float* chsq, float* gram, float* csum,
                       unsigned* gstart, int* gdims,
                       const float* __restrict__ W1, const float* __restrict__ W2,
                       short* __restrict__ W1b, short* __restrict__ W2b) {
  size_t i = (size_t)blockIdx.x * blockDim.x + threadIdx.x;
  size_t stride = (size_t)gridDim.x * blockDim.x;
  if (i < 4096) *(bf16x8*)(W1b + i * 8) = load_frag(W1 + i * 8);
  else if (i < 12288) { size_t j = i - 4096; *(bf16x8*)(W2b + j * 8) = load_frag(W2 + j * 8); }
  for (size_t j = i; j < featN; j += stride) featU[j] = 0u;   // 0 < enc16(any finite)<<16
  for (size_t j = i; j < 65536; j += stride) hist[j] = 0;
  for (size_t j = i; j < 65536u * 3; j += stride) xyzs[j] = 0.f;
  for (size_t j = i; j < 16384; j += stride) gram[j] = 0.f;
  if (i < 256) { chsum[i] = 0.f; chsq[i] = 0.f; }
  if (i < 128) csum[i] = 0.f;
  if (i < 12) gstart[i] = 0x7F800000u;
  if (i < 3) gdims[i] = 0;
}

// ---------------- per-batch xyz min (wave-reduced) ----------------
__global__ void k_min(const float* __restrict__ pos, const int* __restrict__ offs,
                      int N, int nb, unsigned* gstart) {
  int p = blockIdx.x * blockDim.x + threadIdx.x;
  int lane = threadIdx.x & 63;
  int b = -1;
  float v0 = __uint_as_float(0x7F800000u), v1 = v0, v2 = v0;
  if (p < N) {
    b = batch_of(p, offs, nb);
    v0 = pos[p * 3 + 0]; v1 = pos[p * 3 + 1]; v2 = pos[p * 3 + 2];
  }
  int b0 = __shfl(b, 0);
  bool uni = __all(b == b0);
  if (uni) {
    for (int d = 1; d < 64; d <<= 1) {
      v0 = fminf(v0, __shfl_xor(v0, d));
      v1 = fminf(v1, __shfl_xor(v1, d));
      v2 = fminf(v2, __shfl_xor(v2, d));
    }
    if (lane == 0 && b0 >= 0) {
      atomicMin(&gstart[b0 * 3 + 0], __float_as_uint(v0));
      atomicMin(&gstart[b0 * 3 + 1], __float_as_uint(v1));
      atomicMin(&gstart[b0 * 3 + 2], __float_as_uint(v2));
    }
  } else if (p < N) {
    atomicMin(&gstart[b * 3 + 0], __float_as_uint(v0));
    atomicMin(&gstart[b * 3 + 1], __float_as_uint(v1));
    atomicMin(&gstart[b * 3 + 2], __float_as_uint(v2));
  }
}

// ---------------- global coord max (wave-reduced) ----------------
__global__ void k_dims(const float* __restrict__ pos, const int* __restrict__ offs,
                       int N, int nb, const unsigned* gstart, int* gdims) {
  int p = blockIdx.x * blockDim.x + threadIdx.x;
  int lane = threadIdx.x & 63;
  int c0 = 0, c1 = 0, c2 = 0;
  if (p < N) {
    int b = batch_of(p, offs, nb);
    c0 = (int)floorf((pos[p * 3 + 0] - __uint_as_float(gstart[b * 3 + 0])) / GRID_SZ);
    c1 = (int)floorf((pos[p * 3 + 1] - __uint_as_float(gstart[b * 3 + 1])) / GRID_SZ);
    c2 = (int)floorf((pos[p * 3 + 2] - __uint_as_float(gstart[b * 3 + 2])) / GRID_SZ);
  }
  for (int d = 1; d < 64; d <<= 1) {
    c0 = max(c0, __shfl_xor(c0, d));
    c1 = max(c1, __shfl_xor(c1, d));
    c2 = max(c2, __shfl_xor(c2, d));
  }
  if (lane == 0) {
    atomicMax(&gdims[0], c0);
    atomicMax(&gdims[1], c1);
    atomicMax(&gdims[2], c2);
  }
}

// ---------------- lin ids + histogram + xyz sums ----------------
__global__ void k_hist(const float* __restrict__ pos, const int* __restrict__ offs,
                       int N, int nb, const unsigned* gstart, const int* gdims,
                       int* lin, int* hist, float* xyzs) {
  int p = blockIdx.x * blockDim.x + threadIdx.x;
  if (p >= N) return;
  int b = batch_of(p, offs, nb);
  int d0 = gdims[0] + 1, d1 = gdims[1] + 1, d2 = gdims[2] + 1;
  int c[3];
  for (int i = 0; i < 3; i++) {
    float s = __uint_as_float(gstart[b * 3 + i]);
    c[i] = (int)floorf((pos[p * 3 + i] - s) / GRID_SZ);
  }
  int li = ((b * d0 + c[0]) * d1 + c[1]) * d2 + c[2];
  if (li < 0 || li >= 65536) li = 0;
  lin[p] = li;
  atomicAdd(&hist[li], 1);
  atomicAdd(&xyzs[li * 3 + 0], pos[p * 3 + 0]);
  atomicAdd(&xyzs[li * 3 + 1], pos[p * 3 + 1]);
  atomicAdd(&xyzs[li * 3 + 2], pos[p * 3 + 2]);
}

// ---------------- scan stage A ----------------
__global__ __launch_bounds__(1024) void k_scanA(const int* __restrict__ hist,
                                                const int* __restrict__ gdims, int nb,
                                                int2* bsum) {
  __shared__ int so[16], sc2[16];
  int d0 = gdims[0] + 1, d1 = gdims[1] + 1, d2 = gdims[2] + 1;
  int bins = nb * d0 * d1 * d2;
  if (bins > 65536) bins = 65536;
  int i = blockIdx.x * 1024 + threadIdx.x;
  int o = 0, c = 0;
  if (i < bins) { int h = hist[i]; o = (h > 0); c = h; }
  for (int d = 1; d < 64; d <<= 1) { o += __shfl_xor(o, d); c += __shfl_xor(c, d); }
  int w = threadIdx.x >> 6;
  if ((threadIdx.x & 63) == 0) { so[w] = o; sc2[w] = c; }
  __syncthreads();
  if (threadIdx.x == 0) {
    int O = 0, C = 0;
    for (int k = 0; k < 16; k++) { O += so[k]; C += sc2[k]; }
    bsum[blockIdx.x] = make_int2(O, C);
  }
}

// ---------------- scan stage B ----------------
__global__ __launch_bounds__(1024) void k_scanB(const int* __restrict__ hist,
                                                const int* __restrict__ gdims, int nb,
                                                const int2* __restrict__ bsum,
                                                int* rank, int* cursor) {
  __shared__ int so[1024], sc2[1024];
  __shared__ int sbase[2];
  int d0 = gdims[0] + 1, d1 = gdims[1] + 1, d2 = gdims[2] + 1;
  int bins = nb * d0 * d1 * d2;
  if (bins > 65536) bins = 65536;
  int b = blockIdx.x;
  int tid = threadIdx.x;
  if (tid == 0) {
    int O = 0, C = 0;
    for (int k = 0; k < b; k++) { int2 s = bsum[k]; O += s.x; C += s.y; }
    sbase[0] = O; sbase[1] = C;
  }
  int i = b * 1024 + tid;
  int h = (i < bins) ? hist[i] : 0;
  int o = (h > 0), c = h;
  so[tid] = o; sc2[tid] = c;
  __syncthreads();
  for (int off = 1; off < 1024; off <<= 1) {
    int vo = (tid >= off) ? so[tid - off] : 0;
    int vc = (tid >= off) ? sc2[tid - off] : 0;
    __syncthreads();
    so[tid] += vo; sc2[tid] += vc;
    __syncthreads();
  }
  if (i < bins) {
    rank[i]   = sbase[0] + so[tid] - o;
    cursor[i] = sbase[1] + sc2[tid] - c;
  }
  if (i == bins - 1) rank[bins] = sbase[0] + so[tid];   // = M
}

// ---------------- counting-sort scatter + inv write ----------------
__global__ void k_scatter(const int* __restrict__ lin, const int* __restrict__ rank,
                          int* cursor, int N, int* __restrict__ perm,
                          float* __restrict__ out_inv) {
  int p = blockIdx.x * blockDim.x + threadIdx.x;
  if (p >= N) return;
  int li = lin[p];
  out_inv[p] = (float)rank[li];
  int slot = atomicAdd(&cursor[li], 1);
  perm[slot] = p;
}

// ---------------- voxel xyz mean + offset_out ----------------
__global__ void k_voxfin(const int* __restrict__ hist, const int* __restrict__ rank,
                         const float* __restrict__ xyzs, const int* __restrict__ gdims,
                         int nb, float* out_xyz, float* out_off) {
  int d0 = gdims[0] + 1, d1 = gdims[1] + 1, d2 = gdims[2] + 1;
  int dxyz = d0 * d1 * d2;
  int bins = nb * dxyz;
  if (bins > 65536) bins = 65536;
  int i = blockIdx.x * blockDim.x + threadIdx.x;
  if (blockIdx.x == 0 && (int)threadIdx.x < nb) {
    int t = (int)threadIdx.x;
    int idx = (t + 1) * dxyz; if (idx > bins) idx = bins;
    out_off[t] = (float)rank[idx];
  }
  if (i >= bins) return;
  int cnt = hist[i];
  if (cnt <= 0) return;
  int v = rank[i];
  float fc = (float)cnt;
  out_xyz[v * 3 + 0] = xyzs[i * 3 + 0] / fc;
  out_xyz[v * 3 + 1] = xyzs[i * 3 + 1] / fc;
  out_xyz[v * 3 + 2] = xyzs[i * 3 + 2] / fc;
}

// ------- fused convert + Gram: X(f32) -> Xb(bf16); G = Xb^T Xb; column sums --------
#define GCHUNK 1024
__global__ __launch_bounds__(256, 2) void k_convgram(const float* __restrict__ X,
                                                     short* __restrict__ Xb, int N,
                                                     float* __restrict__ gram,
                                                     float* __restrict__ csum) {
  __shared__ short xt[128 * 72];
  __shared__ float lcs[128];
  int tid = threadIdx.x;
  int wid = tid >> 6, lane = tid & 63;
  int lr = lane & 15, lg = lane >> 4;
  int base = blockIdx.x * GCHUNK;
  int cg = tid & 7;                 // 16-channel group this thread loads
  float cs[16];
#pragma unroll
  for (int j = 0; j < 16; j++) cs[j] = 0.f;
  f32x4 acc[2][8];
#pragma unroll
  for (int a = 0; a < 2; a++)
#pragma unroll
    for (int b = 0; b < 8; b++) acc[a][b] = (f32x4){0.f, 0.f, 0.f, 0.f};

  for (int k0 = 0; k0 < GCHUNK; k0 += 64) {
    __syncthreads();   // previous MFMA reads done before overwrite
#pragma unroll
    for (int it = 0; it < 2; it++) {
      int task = tid + it * 256;    // (tid+256)&7 == tid&7, so cg is stable
      int r = task >> 3;            // 0..63
      int row = base + k0 + r;
      bf16x8 v0 = {0,0,0,0,0,0,0,0}, v1 = {0,0,0,0,0,0,0,0};
      if (row < N) {
        const float* src = X + (size_t)row * 128 + cg * 16;
        v0 = load_frag(src);
        v1 = load_frag(src + 8);
        short* dst = Xb + (size_t)row * 128 + cg * 16;
        *(bf16x8*)dst = v0;
        *(bf16x8*)(dst + 8) = v1;
      }
#pragma unroll
      for (int j = 0; j < 8; j++) {
        cs[j]     += __uint_as_float(((unsigned)(unsigned short)v0[j]) << 16);
        cs[j + 8] += __uint_as_float(((unsigned)(unsigned short)v1[j]) << 16);
      }
      int rs = r ^ (cg << 3);       // bank swizzle
#pragma unroll
      for (int j = 0; j < 8; j++) {
        xt[(cg * 16 + j) * 72 + rs]     = v0[j];
        xt[(cg * 16 + 8 + j) * 72 + rs] = v1[j];
      }
    }
    __syncthreads();
#pragma unroll
    for (int ks = 0; ks < 2; ks++) {
      int kk = ks * 32 + lg * 8;
      bf16x8 f[8], af[2];
#pragma unroll
      for (int s = 0; s < 8; s++)
        f[s] = *(const bf16x8*)(xt + (s * 16 + lr) * 72 + (kk ^ (s << 3)));
#pragma unroll
      for (int a = 0; a < 2; a++) {
        int ti = wid * 2 + a;
        af[a] = *(const bf16x8*)(xt + (ti * 16 + lr) * 72 + (kk ^ (ti << 3)));
      }
#pragma unroll
      for (int a = 0; a < 2; a++)
#pragma unroll
        for (int b = 0; b < 8; b++)
          acc[a][b] = __builtin_amdgcn_mfma_f32_16x16x32_bf16(af[a], f[b], acc[a][b], 0, 0, 0);
    }
  }
  // flush partial Gram
#pragma unroll
  for (int a = 0; a < 2; a++)
#pragma unroll
    for (int b = 0; b < 8; b++)
#pragma unroll
      for (int r_ = 0; r_ < 4; r_++) {
        int ci = (wid * 2 + a) * 16 + lg * 4 + r_;
        int cj = b * 16 + lr;
        atomicAdd(&gram[ci * 128 + cj], acc[a][b][r_]);
      }
  // column sums
  if (tid < 128) lcs[tid] = 0.f;
  __syncthreads();
#pragma unroll
  for (int j = 0; j < 16; j++) atomicAdd(&lcs[cg * 16 + j], cs[j]);
  __syncthreads();
  if (tid < 128) atomicAdd(&csum[tid], lcs[tid]);
}

// ---------------- BN affine from Gram: one block per output channel ----------------
__global__ __launch_bounds__(128) void k_finalizeG(const float* __restrict__ gram,
                                                   const float* __restrict__ csum,
                                                   const float* __restrict__ W1,
                                                   const float* __restrict__ b1,
                                                   const float* __restrict__ gamma,
                                                   const float* __restrict__ beta,
                                                   int N, float* Ac, float* Bc) {
  __shared__ float w[128], red[128], red2[128];
  int c = blockIdx.x, j = threadIdx.x;
  w[j] = W1[c * 128 + j];
  __syncthreads();
  float t = 0.f;
  for (int k = 0; k < 128; k++) t += gram[k * 128 + j] * w[k];   // symmetric G
  red[j]  = t * w[j];
  red2[j] = w[j] * csum[j];
  __syncthreads();
  for (int off = 64; off > 0; off >>= 1) {
    if (j < off) { red[j] += red[j + off]; red2[j] += red2[j + off]; }
    __syncthreads();
  }
  if (j == 0) {
    float fn = (float)N;
    float q  = red[0] / fn;        // E[(w.x)^2]
    float md = red2[0] / fn;       // E[w.x]
    float b  = b1[c];
    float mu = md + b;
    float e2 = q + 2.f * b * md + b * b;
    float var = e2 - mu * mu;
    float s = gamma[c] * rsqrtf(var + BN_EPS);
    Ac[c] = s;
    Bc[c] = (b - mu) * s + beta[c];
  }
}

// ---------------- GEMM1 stats pass (fallback when ws too small for Xb) -------------
__global__ __launch_bounds__(256) void k_statsA(const float* __restrict__ X,
                                                const short* __restrict__ W1b,
                                                const float* __restrict__ b1, int N,
                                                float* chsum, float* chsq) {
  int tid = threadIdx.x;
  int wid = tid >> 6, lane = tid & 63;
  int lr = lane & 15, lg = lane >> 4;
  int p0 = blockIdx.x * 64;
  int wcol = wid * 64;
  f32x4 acc[4][4] = {};
  for (int kk = 0; kk < 4; kk++) {
    int k = kk * 32 + lg * 8;
    bf16x8 af[4], bfr[4];
    for (int m = 0; m < 4; m++) {
      int row = p0 + m * 16 + lr; if (row >= N) row = N - 1;
      af[m] = load_frag(X + (size_t)row * 128 + k);
    }
    for (int n = 0; n < 4; n++)
      bfr[n] = *(const bf16x8*)(W1b + (size_t)(wcol + n * 16 + lr) * 128 + k);
    for (int m = 0; m < 4; m++)
      for (int n = 0; n < 4; n++)
        acc[m][n] = __builtin_amdgcn_mfma_f32_16x16x32_bf16(af[m], bfr[n], acc[m][n], 0, 0, 0);
  }
  for (int n = 0; n < 4; n++) {
    int c = wcol + n * 16 + lr;
    float bv = b1[c];
    float s1 = 0.f, s2 = 0.f;
    for (int m = 0; m < 4; m++)
      for (int r = 0; r < 4; r++) {
        int row = p0 + m * 16 + lg * 4 + r;
        if (row < N) {
          float h = acc[m][n][r] + bv;
          s1 += h; s2 += h * h;
        }
      }
    s1 += __shfl_xor(s1, 16); s2 += __shfl_xor(s2, 16);
    s1 += __shfl_xor(s1, 32); s2 += __shfl_xor(s2, 32);
    if (lg == 0) { atomicAdd(&chsum[c], s1); atomicAdd(&chsq[c], s2); }
  }
}

// ---------------- fold BN into per-channel affine (fallback) ----------------
__global__ void k_finalize(const float* chsum, const float* chsq, const float* b1,
                           const float* gamma, const float* beta, int N,
                           float* Ac, float* Bc) {
  int c = threadIdx.x;
  float fn = (float)N;
  float mu = chsum[c] / fn;
  float var = chsq[c] / fn - mu * mu;
  float s = gamma[c] * rsqrtf(var + BN_EPS);
  Ac[c] = s;
  Bc[c] = (b1[c] - mu) * s + beta[c];
}

// ---- fused GEMM1+BN+ReLU+GEMM2, sorted rows, encoded outputs, run-aware flush -----
template <bool XBF>
__global__ __launch_bounds__(256, 3) void k_gemmB(const float* __restrict__ X,
                                                  const short* __restrict__ Xb,
                                                  const short* __restrict__ W1b,
                                                  const short* __restrict__ W2b,
                                                  const float* __restrict__ b2,
                                                  const float* __restrict__ Ac,
                                                  const float* __restrict__ Bc,
                                                  const int* __restrict__ perm,
                                                  const int* __restrict__ lin,
                                                  const int* __restrict__ rank,
                                                  int N, unsigned* __restrict__ featU) {
  __shared__ char smem[64 * 264 * 2];   // ylds (32768) unioned with lmax (33792)
  __shared__ int vox_s[64];
  __shared__ int perm_s[64];
  char* ylds = smem;
  unsigned short* lmax = (unsigned short*)smem;   // [64][264] monotonic-u16, after GEMM2

  int tid = threadIdx.x;
  int wid = tid >> 6, lane = tid & 63;
  int lr = lane & 15, lg = lane >> 4;
  int p0 = blockIdx.x * 64;
  int wcol = wid * 64;

  if (tid < 64) {
    int s = p0 + tid;
    int pp = perm[(s < N) ? s : (N - 1)];
    perm_s[tid] = pp;
    vox_s[tid] = (s < N) ? rank[lin[pp]] : -1;
  }
  __syncthreads();

  // GEMM1: h[64x256] = x[sorted rows, 128] @ W1^T
  f32x4 acc[4][4] = {};
  for (int kk = 0; kk < 4; kk++) {
    int k = kk * 32 + lg * 8;
    bf16x8 af[4], bfr[4];
    for (int m = 0; m < 4; m++) {
      int row = perm_s[m * 16 + lr];
      if (XBF) af[m] = *(const bf16x8*)(Xb + (size_t)row * 128 + k);
      else     af[m] = load_frag(X + (size_t)row * 128 + k);
    }
    for (int n = 0; n < 4; n++)
      bfr[n] = *(const bf16x8*)(W1b + (size_t)(wcol + n * 16 + lr) * 128 + k);
    for (int m = 0; m < 4; m++)
      for (int n = 0; n < 4; n++)
        acc[m][n] = __builtin_amdgcn_mfma_f32_16x16x32_bf16(af[m], bfr[n], acc[m][n], 0, 0, 0);
  }

  // BN + ReLU -> swizzled bf16 in LDS
  for (int n = 0; n < 4; n++) {
    int c = wcol + n * 16 + lr;
    float Av = Ac[c], Bv = Bc[c];
    int colb = c * 2;
    for (int m = 0; m < 4; m++)
      for (int r = 0; r < 4; r++) {
        int row = m * 16 + lg * 4 + r;
        float y = fmaxf(acc[m][n][r] * Av + Bv, 0.0f);
        int addr = (row * 512 + colb) ^ ((row & 7) << 4);
        *(short*)(ylds + addr) = f2bf(y);
      }
  }
  __syncthreads();

  // GEMM2: feats[64x256] = y[64x256] @ W2^T
  f32x4 acc2[4][4] = {};
  for (int kk = 0; kk < 8; kk++) {
    int k = kk * 32 + lg * 8;
    int kb = k * 2;
    bf16x8 af[4], bfr[4];
    for (int m = 0; m < 4; m++) {
      int row = m * 16 + lr;
      af[m] = *(const bf16x8*)(ylds + ((row * 512 + kb) ^ ((row & 7) << 4)));
    }
    for (int n = 0; n < 4; n++)
      bfr[n] = *(const bf16x8*)(W2b + (size_t)(wcol + n * 16 + lr) * 256 + k);
    for (int m = 0; m < 4; m++)
      for (int n = 0; n < 4; n++)
        acc2[m][n] = __builtin_amdgcn_mfma_f32_16x16x32_bf16(af[m], bfr[n], acc2[m][n], 0, 0, 0);
  }
  __syncthreads();   // all ylds reads complete before overwrite

  // single-shot staging: monotonic-u16 (encoded bf16); acc2 dies here
  for (int n = 0; n < 4; n++) {
    int c = wcol + n * 16 + lr;
    float bv = b2[c];
    for (int m = 0; m < 4; m++)
      for (int r = 0; r < 4; r++) {
        int row = m * 16 + lg * 4 + r;
        unsigned us = (unsigned)(unsigned short)f2bf(acc2[m][n][r] + bv);
        us = (us & 0x8000u) ? (~us & 0xFFFFu) : (us | 0x8000u);
        lmax[row * 264 + c] = (unsigned short)us;
      }
  }
  __syncthreads();

  // column pass: segmented max over voxel runs; flush ENCODED u32 (run<<16)
  int nrows = N - p0; if (nrows > 64) nrows = 64;
  int c = tid;
  unsigned run = 0;
  int vprev = vox_s[0];
  int run_start = 0;
  for (int row = 0; row < nrows; row++) {
    int v = vox_s[row];
    if (v != vprev) {
      size_t idx = (size_t)vprev * 256 + c;
      if (run_start > 0) featU[idx] = run << 16;        // block-interior run
      else atomicMax(&featU[idx], run << 16);           // may extend previous block
      run = 0; vprev = v; run_start = row;
    }
    run = max(run, (unsigned)lmax[row * 264 + c]);
  }
  atomicMax(&featU[(size_t)vprev * 256 + c], run << 16); // may extend next block
}

// ---------------- decode all featU entries: monotonic-u16<<16 -> float -------------
__global__ void k_decode(unsigned* featU, size_t n) {
  size_t i = (size_t)blockIdx.x * blockDim.x + threadIdx.x;
  size_t stride = (size_t)gridDim.x * blockDim.x;
  for (; i < n; i += stride) {
    unsigned e = featU[i] >> 16;
    unsigned us = (e & 0x8000u) ? (e & 0x7FFFu) : (~e & 0xFFFFu);
    ((float*)featU)[i] = __uint_as_float(us << 16);
  }
}

extern "C" void kernel_launch(void* const* d_in, const int* in_sizes, int n_in,
                              void* d_out, int out_size, void* d_ws, size_t ws_size,
                              hipStream_t stream) {
  const float* xyz   = (const float*)d_in[0];
  const float* X     = (const float*)d_in[1];
  const int*   offs  = (const int*)d_in[2];
  const float* W1    = (const float*)d_in[3];
  const float* b1    = (const float*)d_in[4];
  const float* gamma = (const float*)d_in[5];
  const float* beta  = (const float*)d_in[6];
  const float* W2    = (const float*)d_in[7];
  const float* b2    = (const float*)d_in[8];

  int N  = in_sizes[0] / 3;
  int nb = in_sizes[2];
  int M  = (out_size - nb - N) / 259;
  if (M <= 0) return;

  char* ws = (char*)d_ws;
  unsigned* gstart = (unsigned*)(ws + WS_START);
  int*   gdims  = (int*)(ws + WS_DIMS);
  float* chsum  = (float*)(ws + WS_CHSUM);
  float* chsq   = (float*)(ws + WS_CHSQ);
  float* Ac     = (float*)(ws + WS_AC);
  float* Bc     = (float*)(ws + WS_BC);
  short* W1b    = (short*)(ws + WS_W1B);
  short* W2b    = (short*)(ws + WS_W2B);
  float* gram   = (float*)(ws + WS_GRAM);
  float* csum   = (float*)(ws + WS_CSUM);
  int*   hist   = (int*)(ws + WS_HIST);
  int*   rank   = (int*)(ws + WS_RANK);
  int*   cursor = (int*)(ws + WS_CURS);
  int2*  bsum   = (int2*)(ws + WS_BSUM);
  float* xyzs   = (float*)(ws + WS_XYZS);
  int*   lin    = (int*)(ws + WS_LIN);
  int*   perm   = (int*)(ws + WS_PERM);
  short* Xb     = (short*)(ws + WS_XB);

  size_t req = (size_t)WS_XB + (size_t)N * 128 * 2;
  bool xbf = ws_size >= req;

  float* out_xyz  = (float*)d_out;
  float* out_feat = out_xyz + (size_t)3 * M;
  float* out_off  = out_feat + (size_t)M * 256;
  float* out_inv  = out_off + nb;
  unsigned* featU = (unsigned*)out_feat;

  int npb = (N + 255) / 256;
  int ngb = (N + 63) / 64;
  int ngr = (N + GCHUNK - 1) / GCHUNK;

  hipLaunchKernelGGL(k_init, dim3(2048), dim3(256), 0, stream,
                     featU, (size_t)M * 256, hist, xyzs, chsum, chsq, gram, csum,
                     gstart, gdims, W1, W2, W1b, W2b);
  if (xbf)
    hipLaunchKernelGGL(k_convgram, dim3(ngr), dim3(256), 0, stream, X, Xb, N, gram, csum);
  hipLaunchKernelGGL(k_min, dim3(npb), dim3(256), 0, stream, xyz, offs, N, nb, gstart);
  hipLaunchKernelGGL(k_dims, dim3(npb), dim3(256), 0, stream, xyz, offs, N, nb, gstart, gdims);
  hipLaunchKernelGGL(k_hist, dim3(npb), dim3(256), 0, stream,
                     xyz, offs, N, nb, gstart, gdims, lin, hist, xyzs);
  hipLaunchKernelGGL(k_scanA, dim3(64), dim3(1024), 0, stream, hist, gdims, nb, bsum);
  hipLaunchKernelGGL(k_scanB, dim3(64), dim3(1024), 0, stream,
                     hist, gdims, nb, bsum, rank, cursor);
  hipLaunchKernelGGL(k_voxfin, dim3(256), dim3(256), 0, stream,
                     hist, rank, xyzs, gdims, nb, out_xyz, out_off);
  hipLaunchKernelGGL(k_scatter, dim3(npb), dim3(256), 0, stream,
                     lin, rank, cursor, N, perm, out_inv);
  if (xbf) {
    hipLaunchKernelGGL(k_finalizeG, dim3(256), dim3(128), 0, stream,
                       gram, csum, W1, b1, gamma, beta, N, Ac, Bc);
    hipLaunchKernelGGL((k_gemmB<true>), dim3(ngb), dim3(256), 0, stream,
                       X, Xb, W1b, W2b, b2, Ac, Bc, perm, lin, rank, N, featU);
  } else {
    hipLaunchKernelGGL(k_statsA, dim3(ngb), dim3(256), 0, stream,
                       X, W1b, b1, N, chsum, chsq);
    hipLaunchKernelGGL(k_finalize, dim3(1), dim3(256), 0, stream,
                       chsum, chsq, b1, gamma, beta, N, Ac, Bc);
    hipLaunchKernelGGL((k_gemmB<false>), dim3(ngb), dim3(256), 0, stream,
                       X, Xb, W1b, W2b, b2, Ac, Bc, perm, lin, rank, N, featU);
  }
  hipLaunchKernelGGL(k_decode, dim3(2048), dim3(256), 0, stream,
                     featU, (size_t)M * 256);
}

// Round 11
// 312.526 us; speedup vs baseline: 1.5640x; 1.5640x over previous
//
#include <hip/hip_runtime.h>
#include <stdint.h>

#define GRID_SZ 0.05f
#define BN_EPS 1e-5f

typedef __attribute__((ext_vector_type(8))) short bf16x8;
typedef __attribute__((ext_vector_type(4))) float f32x4;

// ---------------- ws layout (byte offsets) ----------------
#define WS_START   0         // 12 uints
#define WS_DIMS    64        // 3 ints
#define WS_CHSUM   128       // 256 f
#define WS_CHSQ    1152
#define WS_AC      2176
#define WS_BC      3200
#define WS_W1B     4224      // 256*128 bf16 = 65536
#define WS_W2B     69760     // 256*256 bf16 = 131072
#define WS_GRAM    200832    // 128*128 f = 65536
#define WS_CSUM    266368    // 128 f = 512
#define WS_HIST    266880    // 65536 ints = 262144
#define WS_RANK    529024    // 65537 ints (+pad) = 262208
#define WS_CURS    791296    // 65536 ints = 262144
#define WS_BSUM    1053440   // 64 int2 = 512
#define WS_XYZS    1053952   // 65536*3 f = 786432
#define WS_LIN     1840384   // N ints
#define WS_PERM    2640384   // N ints
#define WS_XB      3440384   // N*128 bf16

__device__ __forceinline__ short f2bf(float f) {
  unsigned u = __float_as_uint(f);
  u += 0x7FFFu + ((u >> 16) & 1u);   // round-to-nearest-even
  return (short)(u >> 16);
}

__device__ __forceinline__ bf16x8 load_frag(const float* p) {
  f32x4 a = *(const f32x4*)p;
  f32x4 b = *(const f32x4*)(p + 4);
  bf16x8 r;
  r[0] = f2bf(a[0]); r[1] = f2bf(a[1]); r[2] = f2bf(a[2]); r[3] = f2bf(a[3]);
  r[4] = f2bf(b[0]); r[5] = f2bf(b[1]); r[6] = f2bf(b[2]); r[7] = f2bf(b[3]);
  return r;
}

__device__ __forceinline__ int batch_of(int p, const int* offs, int nb) {
  int b = 0;
  while (b < nb - 1 && p >= offs[b]) b++;
  return b;
}

// ---------------- f32 -> bf16 X converter ----------------
__global__ void k_conv(const float* __restrict__ src, short* __restrict__ dst, size_t n8) {
  size_t i = (size_t)blockIdx.x * blockDim.x + threadIdx.x;
  size_t stride = (size_t)gridDim.x * blockDim.x;
  for (; i < n8; i += stride)
    *(bf16x8*)(dst + i * 8) = load_frag(src + i * 8);
}

// ---------------- weight converters (one launch) ----------------
__global__ void k_convw(const float* __restrict__ W1, const float* __restrict__ W2,
                        short* __restrict__ W1b, short* __restrict__ W2b) {
  int i = blockIdx.x * blockDim.x + threadIdx.x;   // 0..6143
  if (i < 4096) *(bf16x8*)(W1b + i * 8) = load_frag(W1 + i * 8);
  else { int j = i - 4096; *(bf16x8*)(W2b + j * 8) = load_frag(W2 + j * 8); }
}

// ---------------- init ----------------
__global__ void k_init(unsigned* featU, size_t featN, int* hist, float* xyzs,
                       float* chsum, float* chsq, float* gram, float* csum,
                       unsigned* gstart, int* gdims) {
  size_t i = (size_t)blockIdx.x * blockDim.x + threadIdx.x;
  size_t stride = (size_t)gridDim.x * blockDim.x;
  for (size_t j = i; j < featN; j += stride) featU[j] = 0u;   // 0 < enc16(any finite)<<16
  for (size_t j = i; j < 65536; j += stride) hist[j] = 0;
  for (size_t j = i; j < 65536u * 3; j += stride) xyzs[j] = 0.f;
  for (size_t j = i; j < 16384; j += stride) gram[j] = 0.f;
  if (i < 256) { chsum[i] = 0.f; chsq[i] = 0.f; }
  if (i < 128) csum[i] = 0.f;
  if (i < 12) gstart[i] = 0x7F800000u;
  if (i < 3) gdims[i] = 0;
}

// ---------------- per-batch xyz min ----------------
__global__ void k_min(const float* __restrict__ pos, const int* __restrict__ offs,
                      int N, int nb, unsigned* gstart) {
  __shared__ unsigned smin[12];
  int tid = threadIdx.x;
  if (tid < 12) smin[tid] = 0x7F800000u;
  __syncthreads();
  int p = blockIdx.x * blockDim.x + tid;
  if (p < N) {
    int b = batch_of(p, offs, nb);
    for (int c = 0; c < 3; c++)
      atomicMin(&smin[b * 3 + c], __float_as_uint(pos[p * 3 + c]));
  }
  __syncthreads();
  if (tid < 3 * nb) atomicMin(&gstart[tid], smin[tid]);
}

// ---------------- global coord max ----------------
__global__ void k_dims(const float* __restrict__ pos, const int* __restrict__ offs,
                       int N, int nb, const unsigned* gstart, int* gdims) {
  __shared__ int sd[3];
  int tid = threadIdx.x;
  if (tid < 3) sd[tid] = 0;
  __syncthreads();
  int p = blockIdx.x * blockDim.x + tid;
  if (p < N) {
    int b = batch_of(p, offs, nb);
    for (int c = 0; c < 3; c++) {
      float s = __uint_as_float(gstart[b * 3 + c]);
      int cc = (int)floorf((pos[p * 3 + c] - s) / GRID_SZ);
      atomicMax(&sd[c], cc);
    }
  }
  __syncthreads();
  if (tid < 3) atomicMax(&gdims[tid], sd[tid]);
}

// ---------------- lin ids + histogram + xyz sums ----------------
__global__ void k_hist(const float* __restrict__ pos, const int* __restrict__ offs,
                       int N, int nb, const unsigned* gstart, const int* gdims,
                       int* lin, int* hist, float* xyzs) {
  int p = blockIdx.x * blockDim.x + threadIdx.x;
  if (p >= N) return;
  int b = batch_of(p, offs, nb);
  int d0 = gdims[0] + 1, d1 = gdims[1] + 1, d2 = gdims[2] + 1;
  int c[3];
  for (int i = 0; i < 3; i++) {
    float s = __uint_as_float(gstart[b * 3 + i]);
    c[i] = (int)floorf((pos[p * 3 + i] - s) / GRID_SZ);
  }
  int li = ((b * d0 + c[0]) * d1 + c[1]) * d2 + c[2];
  if (li < 0 || li >= 65536) li = 0;
  lin[p] = li;
  atomicAdd(&hist[li], 1);
  atomicAdd(&xyzs[li * 3 + 0], pos[p * 3 + 0]);
  atomicAdd(&xyzs[li * 3 + 1], pos[p * 3 + 1]);
  atomicAdd(&xyzs[li * 3 + 2], pos[p * 3 + 2]);
}

// ---------------- scan stage A ----------------
__global__ __launch_bounds__(1024) void k_scanA(const int* __restrict__ hist,
                                                const int* __restrict__ gdims, int nb,
                                                int2* bsum) {
  __shared__ int so[16], sc2[16];
  int d0 = gdims[0] + 1, d1 = gdims[1] + 1, d2 = gdims[2] + 1;
  int bins = nb * d0 * d1 * d2;
  if (bins > 65536) bins = 65536;
  int i = blockIdx.x * 1024 + threadIdx.x;
  int o = 0, c = 0;
  if (i < bins) { int h = hist[i]; o = (h > 0); c = h; }
  for (int d = 1; d < 64; d <<= 1) { o += __shfl_xor(o, d); c += __shfl_xor(c, d); }
  int w = threadIdx.x >> 6;
  if ((threadIdx.x & 63) == 0) { so[w] = o; sc2[w] = c; }
  __syncthreads();
  if (threadIdx.x == 0) {
    int O = 0, C = 0;
    for (int k = 0; k < 16; k++) { O += so[k]; C += sc2[k]; }
    bsum[blockIdx.x] = make_int2(O, C);
  }
}

// ---------------- scan stage B ----------------
__global__ __launch_bounds__(1024) void k_scanB(const int* __restrict__ hist,
                                                const int* __restrict__ gdims, int nb,
                                                const int2* __restrict__ bsum,
                                                int* rank, int* cursor) {
  __shared__ int so[1024], sc2[1024];
  __shared__ int sbase[2];
  int d0 = gdims[0] + 1, d1 = gdims[1] + 1, d2 = gdims[2] + 1;
  int bins = nb * d0 * d1 * d2;
  if (bins > 65536) bins = 65536;
  int b = blockIdx.x;
  int tid = threadIdx.x;
  if (tid == 0) {
    int O = 0, C = 0;
    for (int k = 0; k < b; k++) { int2 s = bsum[k]; O += s.x; C += s.y; }
    sbase[0] = O; sbase[1] = C;
  }
  int i = b * 1024 + tid;
  int h = (i < bins) ? hist[i] : 0;
  int o = (h > 0), c = h;
  so[tid] = o; sc2[tid] = c;
  __syncthreads();
  for (int off = 1; off < 1024; off <<= 1) {
    int vo = (tid >= off) ? so[tid - off] : 0;
    int vc = (tid >= off) ? sc2[tid - off] : 0;
    __syncthreads();
    so[tid] += vo; sc2[tid] += vc;
    __syncthreads();
  }
  if (i < bins) {
    rank[i]   = sbase[0] + so[tid] - o;
    cursor[i] = sbase[1] + sc2[tid] - c;
  }
  if (i == bins - 1) rank[bins] = sbase[0] + so[tid];   // = M
}

// ---------------- counting-sort scatter + inv write ----------------
__global__ void k_scatter(const int* __restrict__ lin, const int* __restrict__ rank,
                          int* cursor, int N, int* __restrict__ perm,
                          float* __restrict__ out_inv) {
  int p = blockIdx.x * blockDim.x + threadIdx.x;
  if (p >= N) return;
  int li = lin[p];
  out_inv[p] = (float)rank[li];
  int slot = atomicAdd(&cursor[li], 1);
  perm[slot] = p;
}

// ---------------- voxel xyz mean + offset_out ----------------
__global__ void k_voxfin(const int* __restrict__ hist, const int* __restrict__ rank,
                         const float* __restrict__ xyzs, const int* __restrict__ gdims,
                         int nb, float* out_xyz, float* out_off) {
  int d0 = gdims[0] + 1, d1 = gdims[1] + 1, d2 = gdims[2] + 1;
  int dxyz = d0 * d1 * d2;
  int bins = nb * dxyz;
  if (bins > 65536) bins = 65536;
  int i = blockIdx.x * blockDim.x + threadIdx.x;
  if (blockIdx.x == 0 && (int)threadIdx.x < nb) {
    int t = (int)threadIdx.x;
    int idx = (t + 1) * dxyz; if (idx > bins) idx = bins;
    out_off[t] = (float)rank[idx];
  }
  if (i >= bins) return;
  int cnt = hist[i];
  if (cnt <= 0) return;
  int v = rank[i];
  float fc = (float)cnt;
  out_xyz[v * 3 + 0] = xyzs[i * 3 + 0] / fc;
  out_xyz[v * 3 + 1] = xyzs[i * 3 + 1] / fc;
  out_xyz[v * 3 + 2] = xyzs[i * 3 + 2] / fc;
}

// ---------------- Gram pass: G = Xb^T Xb (128x128) + column sums ----------------
#define GCHUNK 1024
__global__ __launch_bounds__(256, 2) void k_gram(const short* __restrict__ Xb, int N,
                                                 float* __restrict__ gram,
                                                 float* __restrict__ csum) {
  __shared__ short xt[128 * 72];
  __shared__ float lcs[128];
  int tid = threadIdx.x;
  int wid = tid >> 6, lane = tid & 63;
  int lr = lane & 15, lg = lane >> 4;
  int base = blockIdx.x * GCHUNK;
  int cg = tid & 7;                 // 16-channel group this thread loads
  float cs[16];
#pragma unroll
  for (int j = 0; j < 16; j++) cs[j] = 0.f;
  f32x4 acc[2][8];
#pragma unroll
  for (int a = 0; a < 2; a++)
#pragma unroll
    for (int b = 0; b < 8; b++) acc[a][b] = (f32x4){0.f, 0.f, 0.f, 0.f};

  for (int k0 = 0; k0 < GCHUNK; k0 += 64) {
    __syncthreads();   // previous MFMA reads done before overwrite
#pragma unroll
    for (int it = 0; it < 2; it++) {
      int task = tid + it * 256;    // (tid+256)&7 == tid&7, so cg is stable
      int r = task >> 3;            // 0..63
      int row = base + k0 + r;
      bf16x8 v0 = {0,0,0,0,0,0,0,0}, v1 = {0,0,0,0,0,0,0,0};
      if (row < N) {
        const short* src = Xb + (size_t)row * 128 + cg * 16;
        v0 = *(const bf16x8*)src;
        v1 = *(const bf16x8*)(src + 8);
      }
#pragma unroll
      for (int j = 0; j < 8; j++) {
        cs[j]     += __uint_as_float(((unsigned)(unsigned short)v0[j]) << 16);
        cs[j + 8] += __uint_as_float(((unsigned)(unsigned short)v1[j]) << 16);
      }
      int rs = r ^ (cg << 3);       // bank swizzle
#pragma unroll
      for (int j = 0; j < 8; j++) {
        xt[(cg * 16 + j) * 72 + rs]     = v0[j];
        xt[(cg * 16 + 8 + j) * 72 + rs] = v1[j];
      }
    }
    __syncthreads();
#pragma unroll
    for (int ks = 0; ks < 2; ks++) {
      int kk = ks * 32 + lg * 8;
      bf16x8 f[8], af[2];
#pragma unroll
      for (int s = 0; s < 8; s++)
        f[s] = *(const bf16x8*)(xt + (s * 16 + lr) * 72 + (kk ^ (s << 3)));
#pragma unroll
      for (int a = 0; a < 2; a++) {
        int ti = wid * 2 + a;
        af[a] = *(const bf16x8*)(xt + (ti * 16 + lr) * 72 + (kk ^ (ti << 3)));
      }
#pragma unroll
      for (int a = 0; a < 2; a++)
#pragma unroll
        for (int b = 0; b < 8; b++)
          acc[a][b] = __builtin_amdgcn_mfma_f32_16x16x32_bf16(af[a], f[b], acc[a][b], 0, 0, 0);
    }
  }
  // flush partial Gram
#pragma unroll
  for (int a = 0; a < 2; a++)
#pragma unroll
    for (int b = 0; b < 8; b++)
#pragma unroll
      for (int r_ = 0; r_ < 4; r_++) {
        int ci = (wid * 2 + a) * 16 + lg * 4 + r_;
        int cj = b * 16 + lr;
        atomicAdd(&gram[ci * 128 + cj], acc[a][b][r_]);
      }
  // column sums
  if (tid < 128) lcs[tid] = 0.f;
  __syncthreads();
#pragma unroll
  for (int j = 0; j < 16; j++) atomicAdd(&lcs[cg * 16 + j], cs[j]);
  __syncthreads();
  if (tid < 128) atomicAdd(&csum[tid], lcs[tid]);
}

// ---------------- BN affine from Gram: one block per output channel ----------------
__global__ __launch_bounds__(128) void k_finalizeG(const float* __restrict__ gram,
                                                   const float* __restrict__ csum,
                                                   const float* __restrict__ W1,
                                                   const float* __restrict__ b1,
                                                   const float* __restrict__ gamma,
                                                   const float* __restrict__ beta,
                                                   int N, float* Ac, float* Bc) {
  __shared__ float w[128], red[128], red2[128];
  int c = blockIdx.x, j = threadIdx.x;
  w[j] = W1[c * 128 + j];
  __syncthreads();
  float t = 0.f;
  for (int k = 0; k < 128; k++) t += gram[k * 128 + j] * w[k];   // symmetric G
  red[j]  = t * w[j];
  red2[j] = w[j] * csum[j];
  __syncthreads();
  for (int off = 64; off > 0; off >>= 1) {
    if (j < off) { red[j] += red[j + off]; red2[j] += red2[j + off]; }
    __syncthreads();
  }
  if (j == 0) {
    float fn = (float)N;
    float q  = red[0] / fn;        // E[(w.x)^2]
    float md = red2[0] / fn;       // E[w.x]
    float b  = b1[c];
    float mu = md + b;
    float e2 = q + 2.f * b * md + b * b;
    float var = e2 - mu * mu;
    float s = gamma[c] * rsqrtf(var + BN_EPS);
    Ac[c] = s;
    Bc[c] = (b - mu) * s + beta[c];
  }
}

// ---------------- GEMM1 stats pass (fallback when ws too small for Xb) -------------
__global__ __launch_bounds__(256) void k_statsA(const float* __restrict__ X,
                                                const short* __restrict__ W1b,
                                                const float* __restrict__ b1, int N,
                                                float* chsum, float* chsq) {
  int tid = threadIdx.x;
  int wid = tid >> 6, lane = tid & 63;
  int lr = lane & 15, lg = lane >> 4;
  int p0 = blockIdx.x * 64;
  int wcol = wid * 64;
  f32x4 acc[4][4] = {};
  for (int kk = 0; kk < 4; kk++) {
    int k = kk * 32 + lg * 8;
    bf16x8 af[4], bfr[4];
    for (int m = 0; m < 4; m++) {
      int row = p0 + m * 16 + lr; if (row >= N) row = N - 1;
      af[m] = load_frag(X + (size_t)row * 128 + k);
    }
    for (int n = 0; n < 4; n++)
      bfr[n] = *(const bf16x8*)(W1b + (size_t)(wcol + n * 16 + lr) * 128 + k);
    for (int m = 0; m < 4; m++)
      for (int n = 0; n < 4; n++)
        acc[m][n] = __builtin_amdgcn_mfma_f32_16x16x32_bf16(af[m], bfr[n], acc[m][n], 0, 0, 0);
  }
  for (int n = 0; n < 4; n++) {
    int c = wcol + n * 16 + lr;
    float bv = b1[c];
    float s1 = 0.f, s2 = 0.f;
    for (int m = 0; m < 4; m++)
      for (int r = 0; r < 4; r++) {
        int row = p0 + m * 16 + lg * 4 + r;
        if (row < N) {
          float h = acc[m][n][r] + bv;
          s1 += h; s2 += h * h;
        }
      }
    s1 += __shfl_xor(s1, 16); s2 += __shfl_xor(s2, 16);
    s1 += __shfl_xor(s1, 32); s2 += __shfl_xor(s2, 32);
    if (lg == 0) { atomicAdd(&chsum[c], s1); atomicAdd(&chsq[c], s2); }
  }
}

// ---------------- fold BN into per-channel affine (fallback) ----------------
__global__ void k_finalize(const float* chsum, const float* chsq, const float* b1,
                           const float* gamma, const float* beta, int N,
                           float* Ac, float* Bc) {
  int c = threadIdx.x;
  float fn = (float)N;
  float mu = chsum[c] / fn;
  float var = chsq[c] / fn - mu * mu;
  float s = gamma[c] * rsqrtf(var + BN_EPS);
  Ac[c] = s;
  Bc[c] = (b1[c] - mu) * s + beta[c];
}

// ---- fused GEMM1+BN+ReLU+GEMM2, sorted rows, encoded outputs, run-aware flush -----
template <bool XBF>
__global__ __launch_bounds__(256, 3) void k_gemmB(const float* __restrict__ X,
                                                  const short* __restrict__ Xb,
                                                  const short* __restrict__ W1b,
                                                  const short* __restrict__ W2b,
                                                  const float* __restrict__ b2,
                                                  const float* __restrict__ Ac,
                                                  const float* __restrict__ Bc,
                                                  const int* __restrict__ perm,
                                                  const int* __restrict__ lin,
                                                  const int* __restrict__ rank,
                                                  int N, unsigned* __restrict__ featU) {
  __shared__ char smem[64 * 264 * 2];   // ylds (32768) unioned with lmax (33792)
  __shared__ int vox_s[64];
  __shared__ int perm_s[64];
  char* ylds = smem;
  unsigned short* lmax = (unsigned short*)smem;   // [64][264] monotonic-u16, after GEMM2

  int tid = threadIdx.x;
  int wid = tid >> 6, lane = tid & 63;
  int lr = lane & 15, lg = lane >> 4;
  int p0 = blockIdx.x * 64;
  int wcol = wid * 64;

  if (tid < 64) {
    int s = p0 + tid;
    int pp = perm[(s < N) ? s : (N - 1)];
    perm_s[tid] = pp;
    vox_s[tid] = (s < N) ? rank[lin[pp]] : -1;
  }
  __syncthreads();

  // GEMM1: h[64x256] = x[sorted rows, 128] @ W1^T
  f32x4 acc[4][4] = {};
  for (int kk = 0; kk < 4; kk++) {
    int k = kk * 32 + lg * 8;
    bf16x8 af[4], bfr[4];
    for (int m = 0; m < 4; m++) {
      int row = perm_s[m * 16 + lr];
      if (XBF) af[m] = *(const bf16x8*)(Xb + (size_t)row * 128 + k);
      else     af[m] = load_frag(X + (size_t)row * 128 + k);
    }
    for (int n = 0; n < 4; n++)
      bfr[n] = *(const bf16x8*)(W1b + (size_t)(wcol + n * 16 + lr) * 128 + k);
    for (int m = 0; m < 4; m++)
      for (int n = 0; n < 4; n++)
        acc[m][n] = __builtin_amdgcn_mfma_f32_16x16x32_bf16(af[m], bfr[n], acc[m][n], 0, 0, 0);
  }

  // BN + ReLU -> swizzled bf16 in LDS
  for (int n = 0; n < 4; n++) {
    int c = wcol + n * 16 + lr;
    float Av = Ac[c], Bv = Bc[c];
    int colb = c * 2;
    for (int m = 0; m < 4; m++)
      for (int r = 0; r < 4; r++) {
        int row = m * 16 + lg * 4 + r;
        float y = fmaxf(acc[m][n][r] * Av + Bv, 0.0f);
        int addr = (row * 512 + colb) ^ ((row & 7) << 4);
        *(short*)(ylds + addr) = f2bf(y);
      }
  }
  __syncthreads();

  // GEMM2: feats[64x256] = y[64x256] @ W2^T
  f32x4 acc2[4][4] = {};
  for (int kk = 0; kk < 8; kk++) {
    int k = kk * 32 + lg * 8;
    int kb = k * 2;
    bf16x8 af[4], bfr[4];
    for (int m = 0; m < 4; m++) {
      int row = m * 16 + lr;
      af[m] = *(const bf16x8*)(ylds + ((row * 512 + kb) ^ ((row & 7) << 4)));
    }
    for (int n = 0; n < 4; n++)
      bfr[n] = *(const bf16x8*)(W2b + (size_t)(wcol + n * 16 + lr) * 256 + k);
    for (int m = 0; m < 4; m++)
      for (int n = 0; n < 4; n++)
        acc2[m][n] = __builtin_amdgcn_mfma_f32_16x16x32_bf16(af[m], bfr[n], acc2[m][n], 0, 0, 0);
  }
  __syncthreads();   // all ylds reads complete before overwrite

  // single-shot staging: monotonic-u16 (encoded bf16); acc2 dies here
  for (int n = 0; n < 4; n++) {
    int c = wcol + n * 16 + lr;
    float bv = b2[c];
    for (int m = 0; m < 4; m++)
      for (int r = 0; r < 4; r++) {
        int row = m * 16 + lg * 4 + r;
        unsigned us = (unsigned)(unsigned short)f2bf(acc2[m][n][r] + bv);
        us = (us & 0x8000u) ? (~us & 0xFFFFu) : (us | 0x8000u);
        lmax[row * 264 + c] = (unsigned short)us;
      }
  }
  __syncthreads();

  // column pass: segmented max over voxel runs; flush ENCODED u32 (run<<16)
  int nrows = N - p0; if (nrows > 64) nrows = 64;
  int c = tid;
  unsigned run = 0;
  int vprev = vox_s[0];
  int run_start = 0;
  for (int row = 0; row < nrows; row++) {
    int v = vox_s[row];
    if (v != vprev) {
      size_t idx = (size_t)vprev * 256 + c;
      if (run_start > 0) featU[idx] = run << 16;        // block-interior run
      else atomicMax(&featU[idx], run << 16);           // may extend previous block
      run = 0; vprev = v; run_start = row;
    }
    run = max(run, (unsigned)lmax[row * 264 + c]);
  }
  atomicMax(&featU[(size_t)vprev * 256 + c], run << 16); // may extend next block
}

// ---------------- decode all featU entries: monotonic-u16<<16 -> float -------------
__global__ void k_decode(unsigned* featU, size_t n) {
  size_t i = (size_t)blockIdx.x * blockDim.x + threadIdx.x;
  size_t stride = (size_t)gridDim.x * blockDim.x;
  for (; i < n; i += stride) {
    unsigned e = featU[i] >> 16;
    unsigned us = (e & 0x8000u) ? (e & 0x7FFFu) : (~e & 0xFFFFu);
    ((float*)featU)[i] = __uint_as_float(us << 16);
  }
}

extern "C" void kernel_launch(void* const* d_in, const int* in_sizes, int n_in,
                              void* d_out, int out_size, void* d_ws, size_t ws_size,
                              hipStream_t stream) {
  const float* xyz   = (const float*)d_in[0];
  const float* X     = (const float*)d_in[1];
  const int*   offs  = (const int*)d_in[2];
  const float* W1    = (const float*)d_in[3];
  const float* b1    = (const float*)d_in[4];
  const float* gamma = (const float*)d_in[5];
  const float* beta  = (const float*)d_in[6];
  const float* W2    = (const float*)d_in[7];
  const float* b2    = (const float*)d_in[8];

  int N  = in_sizes[0] / 3;
  int nb = in_sizes[2];
  int M  = (out_size - nb - N) / 259;
  if (M <= 0) return;

  char* ws = (char*)d_ws;
  unsigned* gstart = (unsigned*)(ws + WS_START);
  int*   gdims  = (int*)(ws + WS_DIMS);
  float* chsum  = (float*)(ws + WS_CHSUM);
  float* chsq   = (float*)(ws + WS_CHSQ);
  float* Ac     = (float*)(ws + WS_AC);
  float* Bc     = (float*)(ws + WS_BC);
  short* W1b    = (short*)(ws + WS_W1B);
  short* W2b    = (short*)(ws + WS_W2B);
  float* gram   = (float*)(ws + WS_GRAM);
  float* csum   = (float*)(ws + WS_CSUM);
  int*   hist   = (int*)(ws + WS_HIST);
  int*   rank   = (int*)(ws + WS_RANK);
  int*   cursor = (int*)(ws + WS_CURS);
  int2*  bsum   = (int2*)(ws + WS_BSUM);
  float* xyzs   = (float*)(ws + WS_XYZS);
  int*   lin    = (int*)(ws + WS_LIN);
  int*   perm   = (int*)(ws + WS_PERM);
  short* Xb     = (short*)(ws + WS_XB);

  size_t req = (size_t)WS_XB + (size_t)N * 128 * 2;
  bool xbf = ws_size >= req;

  float* out_xyz  = (float*)d_out;
  float* out_feat = out_xyz + (size_t)3 * M;
  float* out_off  = out_feat + (size_t)M * 256;
  float* out_inv  = out_off + nb;
  unsigned* featU = (unsigned*)out_feat;

  int npb = (N + 255) / 256;
  int ngb = (N + 63) / 64;
  int ngr = (N + GCHUNK - 1) / GCHUNK;

  hipLaunchKernelGGL(k_init, dim3(2048), dim3(256), 0, stream,
                     featU, (size_t)M * 256, hist, xyzs, chsum, chsq, gram, csum,
                     gstart, gdims);
  hipLaunchKernelGGL(k_convw, dim3(24), dim3(256), 0, stream, W1, W2, W1b, W2b);
  if (xbf) {
    hipLaunchKernelGGL(k_conv, dim3(4096), dim3(256), 0, stream, X, Xb, (size_t)N * 128 / 8);
    hipLaunchKernelGGL(k_gram, dim3(ngr), dim3(256), 0, stream, Xb, N, gram, csum);
  }
  hipLaunchKernelGGL(k_min, dim3(npb), dim3(256), 0, stream, xyz, offs, N, nb, gstart);
  hipLaunchKernelGGL(k_dims, dim3(npb), dim3(256), 0, stream, xyz, offs, N, nb, gstart, gdims);
  hipLaunchKernelGGL(k_hist, dim3(npb), dim3(256), 0, stream,
                     xyz, offs, N, nb, gstart, gdims, lin, hist, xyzs);
  hipLaunchKernelGGL(k_scanA, dim3(64), dim3(1024), 0, stream, hist, gdims, nb, bsum);
  hipLaunchKernelGGL(k_scanB, dim3(64), dim3(1024), 0, stream,
                     hist, gdims, nb, bsum, rank, cursor);
  hipLaunchKernelGGL(k_voxfin, dim3(256), dim3(256), 0, stream,
                     hist, rank, xyzs, gdims, nb, out_xyz, out_off);
  hipLaunchKernelGGL(k_scatter, dim3(npb), dim3(256), 0, stream,
                     lin, rank, cursor, N, perm, out_inv);
  if (xbf) {
    hipLaunchKernelGGL(k_finalizeG, dim3(256), dim3(128), 0, stream,
                       gram, csum, W1, b1, gamma, beta, N, Ac, Bc);
    hipLaunchKernelGGL((k_gemmB<true>), dim3(ngb), dim3(256), 0, stream,
                       X, Xb, W1b, W2b, b2, Ac, Bc, perm, lin, rank, N, featU);
  } else {
    hipLaunchKernelGGL(k_statsA, dim3(ngb), dim3(256), 0, stream,
                       X, W1b, b1, N, chsum, chsq);
    hipLaunchKernelGGL(k_finalize, dim3(1), dim3(256), 0, stream,
                       chsum, chsq, b1, gamma, beta, N, Ac, Bc);
    hipLaunchKernelGGL((k_gemmB<false>), dim3(ngb), dim3(256), 0, stream,
                       X, Xb, W1b, W2b, b2, Ac, Bc, perm, lin, rank, N, featU);
  }
  hipLaunchKernelGGL(k_decode, dim3(2048), dim3(256), 0, stream,
                     featU, (size_t)M * 256);
}